// Round 1
// baseline (262.647 us; speedup 1.0000x reference)
//
#include <hip/hip_runtime.h>

// Conv2d 3x3 valid, C_in=8, C_out=8, H=W=2048, fp32.
// x: (8, 2048, 2048), weight: (8, 8, 3, 3), out: (8, 2046, 2046).

#define H_IN   2048
#define W_IN   2048
#define H_OUT  2046
#define W_OUT  2046
#define CIN    8
#define COUT   8

// Each thread: 4 consecutive ow at one oh, all 8 output channels.
// Threads per output row: ceil(2046/4) = 512.
#define TPR 512

__global__ __launch_bounds__(256)
void conv3x3_kernel(const float* __restrict__ x,
                    const float* __restrict__ w,
                    float* __restrict__ out) {
    const int gtid = blockIdx.x * blockDim.x + threadIdx.x;
    const int oh = gtid / TPR;
    const int tw = gtid - oh * TPR;
    const int ow = tw * 4;
    if (oh >= H_OUT) return;

    const bool full = (ow + 4 <= W_OUT);   // tail tile (ow=2044) has 2 valid cols

    float acc[COUT][4];
    #pragma unroll
    for (int co = 0; co < COUT; ++co)
        #pragma unroll
        for (int p = 0; p < 4; ++p)
            acc[co][p] = 0.0f;

    // ci loop kept as a runtime loop (I-cache friendly); weight offsets stay
    // wave-uniform so the compiler emits scalar s_loads through K$.
    for (int ci = 0; ci < CIN; ++ci) {
        #pragma unroll
        for (int kh = 0; kh < 3; ++kh) {
            const float* p = x + ((size_t)ci * H_IN + (size_t)(oh + kh)) * W_IN + ow;
            float in[6];
            // float4 @ 16B-aligned (W_IN=2048 and ow both multiples of 4)
            const float4 v4 = *reinterpret_cast<const float4*>(p);
            in[0] = v4.x; in[1] = v4.y; in[2] = v4.z; in[3] = v4.w;
            if (full) {
                const float2 v2 = *reinterpret_cast<const float2*>(p + 4);
                in[4] = v2.x; in[5] = v2.y;
            } else {
                in[4] = 0.0f; in[5] = 0.0f;   // tail: px 2,3 never stored
            }
            #pragma unroll
            for (int co = 0; co < COUT; ++co) {
                #pragma unroll
                for (int kw = 0; kw < 3; ++kw) {
                    const float wt = w[((co * CIN + ci) * 3 + kh) * 3 + kw];
                    #pragma unroll
                    for (int px = 0; px < 4; ++px)
                        acc[co][px] = fmaf(wt, in[kw + px], acc[co][px]);
                }
            }
        }
    }

    #pragma unroll
    for (int co = 0; co < COUT; ++co) {
        float* o = out + ((size_t)co * H_OUT + (size_t)oh) * W_OUT + ow;
        // rows are only 8B-aligned (W_OUT=2046) -> float2 stores
        *reinterpret_cast<float2*>(o) = make_float2(acc[co][0], acc[co][1]);
        if (full)
            *reinterpret_cast<float2*>(o + 2) = make_float2(acc[co][2], acc[co][3]);
    }
}

extern "C" void kernel_launch(void* const* d_in, const int* in_sizes, int n_in,
                              void* d_out, int out_size, void* d_ws, size_t ws_size,
                              hipStream_t stream) {
    const float* x = (const float*)d_in[0];
    const float* w = (const float*)d_in[1];
    float* out = (float*)d_out;

    const int total_threads = H_OUT * TPR;          // 2046 * 512 = 1,047,552
    const int block = 256;
    const int grid = (total_threads + block - 1) / block;  // 4092

    conv3x3_kernel<<<grid, block, 0, stream>>>(x, w, out);
}

// Round 2
// 254.268 us; speedup vs baseline: 1.0330x; 1.0330x over previous
//
#include <hip/hip_runtime.h>

// Conv2d 3x3 valid, C_in=8, C_out=8, H=W=2048, fp32.
// x: (8, 2048, 2048), weight: (8, 8, 3, 3), out: (8, 2046, 2046).
//
// v2: thread tile = 4 wide x 2 high, all 8 C_out in registers.
//   - vertical register reuse: 4 input rows serve 2 output rows (raw re-read
//     2x instead of 3x; L2/L3 absorbs the remaining group-boundary sharing)
//   - 64 accumulators + 24 input regs -> ~120 VGPR: room for the compiler to
//     pipeline the 8 row-loads per ci ahead of the 576-FMA block.

#define H_IN   2048
#define W_IN   2048
#define H_OUT  2046
#define W_OUT  2046
#define CIN    8
#define COUT   8

#define TPR 512            // thread-columns per row-group (4 px each)
#define NGROUPS 1023       // 2046 / 2 output rows per thread

__global__ __launch_bounds__(256)
void conv3x3_v2(const float* __restrict__ x,
                const float* __restrict__ w,
                float* __restrict__ out) {
    const int gtid = blockIdx.x * 256 + threadIdx.x;
    const int g  = gtid / TPR;          // row group (2 output rows)
    const int tw = gtid - g * TPR;
    const int oh = g * 2;
    const int ow = tw * 4;

    const bool full = (tw != TPR - 1);  // tail tile (ow=2044): only 2 valid cols

    float acc[2][COUT][4];
    #pragma unroll
    for (int r = 0; r < 2; ++r)
        #pragma unroll
        for (int co = 0; co < COUT; ++co)
            #pragma unroll
            for (int p = 0; p < 4; ++p)
                acc[r][co][p] = 0.0f;

    // runtime ci loop: body (~8 loads + 576 FMA) stays I$-resident; compiler
    // is free to software-pipeline loads across iterations.
    for (int ci = 0; ci < CIN; ++ci) {
        // load 4 input rows x 6 cols
        float in[4][6];
        #pragma unroll
        for (int r = 0; r < 4; ++r) {
            const float* p = x + ((size_t)ci * H_IN + (size_t)(oh + r)) * W_IN + ow;
            const float4 v4 = *reinterpret_cast<const float4*>(p);   // 16B aligned
            in[r][0] = v4.x; in[r][1] = v4.y; in[r][2] = v4.z; in[r][3] = v4.w;
            if (full) {
                const float2 v2 = *reinterpret_cast<const float2*>(p + 4);
                in[r][4] = v2.x; in[r][5] = v2.y;
            } else {
                in[r][4] = 0.0f; in[r][5] = 0.0f;  // px 2,3 never stored on tail
            }
        }

        // input row r feeds output row 0 with kh=r (r<3) and row 1 with kh=r-1 (r>=1)
        #pragma unroll
        for (int r = 0; r < 4; ++r) {
            #pragma unroll
            for (int co = 0; co < COUT; ++co) {
                #pragma unroll
                for (int kw = 0; kw < 3; ++kw) {
                    if (r < 3) {
                        const float wt = w[((co * CIN + ci) * 3 + r) * 3 + kw];
                        #pragma unroll
                        for (int px = 0; px < 4; ++px)
                            acc[0][co][px] = fmaf(wt, in[r][kw + px], acc[0][co][px]);
                    }
                    if (r >= 1) {
                        const float wt = w[((co * CIN + ci) * 3 + (r - 1)) * 3 + kw];
                        #pragma unroll
                        for (int px = 0; px < 4; ++px)
                            acc[1][co][px] = fmaf(wt, in[r][kw + px], acc[1][co][px]);
                    }
                }
            }
        }
    }

    #pragma unroll
    for (int r = 0; r < 2; ++r) {
        #pragma unroll
        for (int co = 0; co < COUT; ++co) {
            float* o = out + ((size_t)co * H_OUT + (size_t)(oh + r)) * W_OUT + ow;
            // rows alternate 16B/8B alignment (W_OUT=2046) -> float2 stores
            *reinterpret_cast<float2*>(o) = make_float2(acc[r][co][0], acc[r][co][1]);
            if (full)
                *reinterpret_cast<float2*>(o + 2) = make_float2(acc[r][co][2], acc[r][co][3]);
        }
    }
}

extern "C" void kernel_launch(void* const* d_in, const int* in_sizes, int n_in,
                              void* d_out, int out_size, void* d_ws, size_t ws_size,
                              hipStream_t stream) {
    const float* x = (const float*)d_in[0];
    const float* w = (const float*)d_in[1];
    float* out = (float*)d_out;

    const int total_threads = NGROUPS * TPR;        // 1023 * 512 = 523,776
    const int block = 256;
    const int grid = total_threads / block;         // 2046 exactly

    conv3x3_v2<<<grid, block, 0, stream>>>(x, w, out);
}